// Round 11
// baseline (214.148 us; speedup 1.0000x reference)
//
#include <hip/hip_runtime.h>

#define Bq 2
#define Nn 6
#define Dd 48
#define Hh 28
#define Ww 60
#define Cc 64
#define Xd 200
#define Yd 200
#define NP (Nn*Dd*Hh*Ww)      // 483840 points per batch
#define TOTP (Bq*NP)          // 967680 total points
#define NVOX (Xd*Yd)          // 40000 voxels per batch (Z=1)
#define NSEG (Bq*NVOX)        // 80000 segments
#define NB1  79               // ceil(NSEG/1024)

// Zero the histogram ourselves: rocclr fillBufferAligned is pathologically slow
__global__ __launch_bounds__(1024) void zero_cnt(int* __restrict__ cnt)
{
    int i = blockIdx.x * 1024 + threadIdx.x;
    if (i < NSEG) cnt[i] = 0;
}

// ---------------------------------------------------------------------------
// Phase A: voxelize each point, store segment id (-1 invalid), histogram count
// ---------------------------------------------------------------------------
__global__ __launch_bounds__(256) void phase_a(
    const float* __restrict__ geom, int* __restrict__ rank, int* __restrict__ cnt)
{
    int p = blockIdx.x * 256 + threadIdx.x;
    if (p >= TOTP) return;
    float gx = geom[(long)p*3 + 0];
    float gy = geom[(long)p*3 + 1];
    float gz = geom[(long)p*3 + 2];
    // must match numpy astype(int32): truncate toward zero, f32 arithmetic
    int vx = (int)((gx + 50.0f) / 0.5f);
    int vy = (int)((gy + 50.0f) / 0.5f);
    int vz = (int)((gz + 10.0f) / 20.0f);
    int seg = -1;
    if (vx >= 0 && vx < Xd && vy >= 0 && vy < Yd && vz == 0) {
        int b = (p >= NP) ? 1 : 0;
        seg = b * NVOX + vx * Yd + vy;
        atomicAdd(&cnt[seg], 1);
    }
    rank[p] = seg;
}

// Scan P1: per-1024-block exclusive scan of cnt -> start, block totals -> bsum
__global__ __launch_bounds__(1024) void scan_p1(
    const int* __restrict__ cnt, int* __restrict__ start, int* __restrict__ bsum)
{
    __shared__ int sh[1024];
    int tid = threadIdx.x;
    int i = blockIdx.x * 1024 + tid;
    int v = (i < NSEG) ? cnt[i] : 0;
    sh[tid] = v;
    __syncthreads();
    for (int off = 1; off < 1024; off <<= 1) {
        int t = (tid >= off) ? sh[tid - off] : 0;
        __syncthreads();
        sh[tid] += t;
        __syncthreads();
    }
    if (i < NSEG) start[i] = sh[tid] - v;
    if (tid == 1023) bsum[blockIdx.x] = sh[1023];
}

// Scan P2: exclusive scan of block totals (single block)
__global__ __launch_bounds__(128) void scan_p2(int* __restrict__ bsum)
{
    __shared__ int sh[128];
    int tid = threadIdx.x;
    int v = (tid < NB1) ? bsum[tid] : 0;
    sh[tid] = v;
    __syncthreads();
    for (int off = 1; off < 128; off <<= 1) {
        int t = (tid >= off) ? sh[tid - off] : 0;
        __syncthreads();
        sh[tid] += t;
        __syncthreads();
    }
    if (tid < NB1) bsum[tid] = sh[tid] - v;
}

// Scan P3: add block offsets
__global__ __launch_bounds__(1024) void scan_p3(
    int* __restrict__ start, const int* __restrict__ bsum)
{
    int i = blockIdx.x * 1024 + threadIdx.x;
    if (i < NSEG) start[i] += bsum[blockIdx.x];
}

// ---------------------------------------------------------------------------
// Phase C': payload permutation. One wave per TWO points (half-wave each).
// Sequential coalesced read of x rows (256B per point), f16 conversion,
// 128B row scattered to its segment-sorted slot perm[pos] (posted stores,
// L3-resident 124MB array -> no DRAM scatter penalty). No random reads.
// start[] is bumped to end-pointers as a side effect (consumed by phase_d).
// ---------------------------------------------------------------------------
__global__ __launch_bounds__(256) void phase_c_pay(
    const int* __restrict__ rank, int* __restrict__ start,
    const float* __restrict__ x, unsigned int* __restrict__ perm)
{
    int w    = blockIdx.x * 4 + (threadIdx.x >> 6);  // wave id (points 2w, 2w+1)
    int lane = threadIdx.x & 63;
    int half = lane >> 5;                            // 0: point 2w, 1: point 2w+1
    int li   = lane & 31;
    int p    = 2 * w + half;                         // grid exact: p < TOTP

    int seg = rank[p];                               // 2 addrs/wave, broadcast
    bool valid = seg >= 0;
    int pos = 0;
    if (li == 0 && valid) pos = atomicAdd(&start[seg], 1);
    pos = __shfl(pos, half << 5);                    // full-wave shfl, uniform flow

    if (valid) {
        const float2 v = *(const float2*)(x + (size_t)p * Cc + 2 * li);
        _Float16 h0 = (_Float16)v.x, h1 = (_Float16)v.y;
        unsigned int u = (unsigned int)__builtin_bit_cast(unsigned short, h0)
                       | ((unsigned int)__builtin_bit_cast(unsigned short, h1) << 16);
        perm[(size_t)pos * 32 + li] = u;             // 128B contiguous per half-wave
    }
}

// ---------------------------------------------------------------------------
// Phase D: 32 voxels per block (8/wave). Wave's 8 segments occupy a
// CONTIGUOUS slice of perm[] -> purely sequential coalesced reads (64 lanes
// = 2 rows x 128B per step; halves take alternating rows). Per-voxel
// unrolled register accumulation (static indexing), shfl_xor(32) reduce
// across halves, LDS transpose tile, coalesced out[b][c][xy] writes.
// No atomics, no random reads.
// ---------------------------------------------------------------------------
#define VOX_LOOP(v, rA, rB) \
    for (int r = (rA) + half; r < (rB); r += 2) { \
        unsigned int u = base[(size_t)r * 32]; \
        float lo = (float)__builtin_bit_cast(_Float16, (unsigned short)(u & 0xffffu)); \
        float hi = (float)__builtin_bit_cast(_Float16, (unsigned short)(u >> 16)); \
        Alo[v] += lo; Ahi[v] += hi; \
    }

__global__ __launch_bounds__(256) void phase_d(
    const int* __restrict__ endp, const unsigned int* __restrict__ perm,
    float* __restrict__ out)
{
    __shared__ float tile[32][66];         // float2 writes, 2-way banks (free)
    int blk  = blockIdx.x;                 // 0 .. 2499
    int b    = blk / (NVOX/32);            // 1250 blocks per batch
    int xy0  = (blk % (NVOX/32)) * 32;
    int wv   = threadIdx.x >> 6;           // 0..3
    int lane = threadIdx.x & 63;
    int half = lane >> 5;                  // row parity
    int li   = lane & 31;                  // channel-pair index
    int seg0 = b * NVOX + xy0 + wv * 8;    // this wave's first voxel

    // lane j<9 loads boundary end[seg0-1+j]; e[v]=begin of voxel v, e[v+1]=end
    int e = 0;
    if (lane < 9) {
        int idx = seg0 - 1 + lane;
        e = (idx >= 0) ? endp[idx] : 0;
    }
    int eb0 = __shfl(e, 0);
    int rb1 = __shfl(e,1) - eb0, rb2 = __shfl(e,2) - eb0,
        rb3 = __shfl(e,3) - eb0, rb4 = __shfl(e,4) - eb0,
        rb5 = __shfl(e,5) - eb0, rb6 = __shfl(e,6) - eb0,
        rb7 = __shfl(e,7) - eb0, rb8 = __shfl(e,8) - eb0;

    float Alo[8], Ahi[8];
    #pragma unroll
    for (int v = 0; v < 8; ++v) { Alo[v] = 0.0f; Ahi[v] = 0.0f; }

    const unsigned int* base = perm + (size_t)eb0 * 32 + li;
    VOX_LOOP(0, 0,   rb1)
    VOX_LOOP(1, rb1, rb2)
    VOX_LOOP(2, rb2, rb3)
    VOX_LOOP(3, rb3, rb4)
    VOX_LOOP(4, rb4, rb5)
    VOX_LOOP(5, rb5, rb6)
    VOX_LOOP(6, rb6, rb7)
    VOX_LOOP(7, rb7, rb8)

    // combine the two row-parity halves (lanes l and l^32 share chPair li)
    #pragma unroll
    for (int v = 0; v < 8; ++v) {
        Alo[v] += __shfl_xor(Alo[v], 32);
        Ahi[v] += __shfl_xor(Ahi[v], 32);
    }
    if (half == 0) {
        #pragma unroll
        for (int v = 0; v < 8; ++v)
            *(float2*)&tile[wv*8 + v][2*li] = make_float2(Alo[v], Ahi[v]);
    }
    __syncthreads();

    // out[b][c][xy0+xy]: iteration s writes 8 channels x 32 xy
    float* dst = out + (long)b * Cc * NVOX + xy0;
    int xy = threadIdx.x & 31;
    int c0 = threadIdx.x >> 5;             // 0..7
    #pragma unroll
    for (int s = 0; s < 8; ++s) {
        int c = s * 8 + c0;
        dst[(long)c * NVOX + xy] = tile[xy][c];
    }
}

// ---------------------------------------------------------------------------
// Fallback (r1 atomic path) if ws is unexpectedly small
// ---------------------------------------------------------------------------
__global__ __launch_bounds__(256) void fiery_scatter_direct(
    const float* __restrict__ x, const float* __restrict__ geom,
    float* __restrict__ out)
{
    int wid  = blockIdx.x * 4 + (threadIdx.x >> 6);
    int lane = threadIdx.x & 63;
    if (wid >= TOTP) return;
    long gb = (long)wid * 3;
    float gx = geom[gb+0], gy = geom[gb+1], gz = geom[gb+2];
    int vx = (int)((gx + 50.0f) / 0.5f);
    int vy = (int)((gy + 50.0f) / 0.5f);
    int vz = (int)((gz + 10.0f) / 20.0f);
    if (!(vx >= 0 && vx < Xd && vy >= 0 && vy < Yd && vz == 0)) return;
    int b = (wid >= NP) ? 1 : 0;
    float vv = x[(long)wid * Cc + lane];
    long dst = ((long)(b * Cc + lane)) * NVOX + (vx * Yd + vy);
    atomicAdd(&out[dst], vv);
}

extern "C" void kernel_launch(void* const* d_in, const int* in_sizes, int n_in,
                              void* d_out, int out_size, void* d_ws, size_t ws_size,
                              hipStream_t stream)
{
    const float* x    = (const float*)d_in[0];
    const float* geom = (const float*)d_in[1];
    float* out = (float*)d_out;

    // ws layout: rank[TOTP] | cnt[NSEG] | start[NSEG] | bsum[128] | perm[TOTP*32 u32]
    size_t need = ((size_t)TOTP + (size_t)NSEG * 2 + 128 + (size_t)TOTP * 32)
                  * sizeof(int);
    if (ws_size >= need) {
        int* rank  = (int*)d_ws;
        int* cnt   = rank  + TOTP;
        int* start = cnt   + NSEG;
        int* bsum  = start + NSEG;
        unsigned int* perm = (unsigned int*)(bsum + 128);

        zero_cnt<<<NB1, 1024, 0, stream>>>(cnt);
        phase_a<<<TOTP/256, 256, 0, stream>>>(geom, rank, cnt);
        scan_p1<<<NB1, 1024, 0, stream>>>(cnt, start, bsum);
        scan_p2<<<1, 128, 0, stream>>>(bsum);
        scan_p3<<<NB1, 1024, 0, stream>>>(start, bsum);
        phase_c_pay<<<TOTP/8, 256, 0, stream>>>(rank, start, x, perm);
        phase_d<<<Bq*(NVOX/32), 256, 0, stream>>>(start, perm, out);
    } else {
        hipMemsetAsync(out, 0, (size_t)out_size * sizeof(float), stream);
        fiery_scatter_direct<<<TOTP/4, 256, 0, stream>>>(x, geom, out);
    }
}